// Round 2
// baseline (1201.389 us; speedup 1.0000x reference)
//
#include <hip/hip_runtime.h>
#include <math.h>

#define NEGV -1e30f
#define NEGH -60000.0f      // "log-zero" representable in fp16

constexpr int SSTRIDE = 264;  // padded extended-state stride (max S=257, pad for 8B alignment)

struct alignas(8) H4 { _Float16 h[4]; };

// Gather kernel: em[(b*T+t)*SSTRIDE + s] = (fp16) lp[b,t,ext[s]], NEGH for s >= Sb.
// One wave per (b,t) row; rows with t >= input_len are skipped (never read by DP).
__global__ __launch_bounds__(256) void gather_kernel(
    const float* __restrict__ lp, const int* __restrict__ targets,
    const int* __restrict__ ilen, const int* __restrict__ tlen,
    _Float16* __restrict__ em, int B, int T, int C, int L) {
  const int wave = threadIdx.x >> 6;
  const int lane = threadIdx.x & 63;
  const int row = blockIdx.x * 4 + wave;
  if (row >= B * T) return;
  const int b = row / T;
  const int t = row - b * T;
  if (t >= ilen[b]) return;
  const int tl = tlen[b];
  const int* tg = targets + (size_t)b * L;
  const float* src = lp + (size_t)row * C;
  _Float16* dst = em + (size_t)row * SSTRIDE;

#pragma unroll
  for (int k = 0; k < 4; ++k) {
    int s = lane + 64 * k;                  // 0..255
    float v;
    if (s & 1) {
      int li = (s - 1) >> 1;                // li <= 127 < L
      v = (li < tl) ? src[tg[li]] : NEGH;   // odd s valid iff li < tl
    } else {
      v = ((s >> 1) <= tl) ? src[0] : NEGH; // even s valid iff s <= 2*tl
    }
    dst[s] = (_Float16)v;
  }
  if (lane < 8) {
    int s = 256 + lane;                     // 256..263 (pad slots get NEGH)
    float v;
    if (s & 1) {
      int li = (s - 1) >> 1;
      v = (li < tl && li < L) ? src[tg[li]] : NEGH;
    } else {
      v = ((s >> 1) <= tl) ? src[0] : NEGH;
    }
    dst[s] = (_Float16)v;
  }
}

// DP kernel: one wave per batch element. Lane l owns states 4l..4l+3 in a[0..3]
// plus a redundant copy of state 4l+4 in a[4] (so shfl_up(a[3])/shfl_up(a[2])
// deliver alpha[s-1]/alpha[s-2]). Emissions come from the dense em matrix:
// one 8B vector load + one 2B scalar load per lane per step, prefetch depth 8.
__global__ __launch_bounds__(64) void ctc_dp_kernel(
    const _Float16* __restrict__ em, const int* __restrict__ targets,
    const int* __restrict__ ilen, const int* __restrict__ tlen,
    float* __restrict__ out, int T, int L) {
  const int b = blockIdx.x;
  const int l = threadIdx.x;
  const int len = ilen[b];
  const int tl = tlen[b];
  const int Sb = 2 * tl + 1;
  const int* tg = targets + (size_t)b * L;
  const _Float16* base = em + (size_t)b * T * SSTRIDE;

  bool sk[5];
#pragma unroll
  for (int j = 0; j < 5; ++j) {
    int s = 4 * l + j;                       // <= 256
    int li = (s - 1) >> 1;
    sk[j] = ((s & 1) && s >= 3 && s < Sb) ? (tg[li] != tg[li - 1]) : false;
  }

  // t = 0: only states 0,1 alive (always valid since Sb >= 129)
  float a[5];
#pragma unroll
  for (int j = 0; j < 5; ++j) {
    int s = 4 * l + j;
    a[j] = (s < 2) ? (float)base[s] : NEGV;
  }

  auto loadg = [&](float g[5], int t) {
    const _Float16* r = base + (size_t)t * SSTRIDE + 4 * l;
    H4 v = *(const H4*)r;                    // states 4l..4l+3
#pragma unroll
    for (int j = 0; j < 4; ++j) g[j] = (float)v.h[j];
    g[4] = (float)r[4];                      // state 4l+4
  };

  auto step = [&](const float g[5]) {
    float up1 = __shfl_up(a[3], 1, 64);      // alpha[4l-1]
    float up2 = __shfl_up(a[2], 1, 64);      // alpha[4l-2]
    if (l == 0) { up1 = NEGV; up2 = NEGV; }
    float p1[5] = {up1, a[0], a[1], a[2], a[3]};
    float p2[5] = {up2, up1, a[0], a[1], a[2]};
#pragma unroll
    for (int j = 0; j < 5; ++j) {
      float q0 = a[j];
      float q1 = p1[j];
      float q2 = sk[j] ? p2[j] : NEGV;
      float m = fmaxf(q0, fmaxf(q1, q2));
      float ss = __expf(q0 - m) + __expf(q1 - m) + __expf(q2 - m);
      a[j] = g[j] + m + __logf(ss);          // validity folded into g (NEGH)
    }
  };

  constexpr int PD = 8;
  float g[PD][5];
#pragma unroll
  for (int d = 0; d < PD; ++d) {
    int idx = 1 + d; if (idx >= len) idx = len - 1;
    loadg(g[d], idx);
  }
  int t = 1;
  for (; t + PD - 1 < len; t += PD) {
#pragma unroll
    for (int d = 0; d < PD; ++d) {
      step(g[d]);
      int idx = t + d + PD; if (idx >= len) idx = len - 1;  // clamp: never consumed
      loadg(g[d], idx);
    }
  }
  for (int d = 0; t < len; ++t, ++d) step(g[d]);

  // epilogue: logaddexp(alpha[Sb-1], alpha[Sb-2]); norm term analytically ~0
  __shared__ float af[257];
#pragma unroll
  for (int j = 0; j < 4; ++j) af[4 * l + j] = a[j];
  if (l == 63) af[256] = a[4];
  __syncthreads();
  if (l == 0) {
    float a1 = af[Sb - 1];
    float a2 = af[Sb - 2];
    float m = fmaxf(a1, a2);
    float llh = m + __logf(__expf(a1 - m) + __expf(a2 - m));
    out[b] = -llh;
  }
}

extern "C" void kernel_launch(void* const* d_in, const int* in_sizes, int n_in,
                              void* d_out, int out_size, void* d_ws, size_t ws_size,
                              hipStream_t stream) {
  const float* lp = (const float*)d_in[0];
  const int* targets = (const int*)d_in[1];
  const int* ilen = (const int*)d_in[2];
  const int* tlen = (const int*)d_in[3];
  float* out = (float*)d_out;

  const int B = in_sizes[2];               // 32
  const int L = in_sizes[1] / B;           // 128
  const int C = 1024;                      // per reference
  const int T = in_sizes[0] / (B * C);     // 1600

  _Float16* em = (_Float16*)d_ws;          // B*T*SSTRIDE fp16 = ~27 MB

  const int rows = B * T;
  gather_kernel<<<(rows + 3) / 4, 256, 0, stream>>>(lp, targets, ilen, tlen, em, B, T, C, L);
  ctc_dp_kernel<<<B, 64, 0, stream>>>(em, targets, ilen, tlen, out, T, L);
}

// Round 3
// 551.740 us; speedup vs baseline: 2.1775x; 2.1775x over previous
//
#include <hip/hip_runtime.h>
#include <math.h>

#define NEGV -1e30f
#define NEGH -60000.0f      // "log-zero" sentinel, fp16-representable
#define LOG2E 1.44269504088896f
#define LN2   0.69314718055995f

constexpr int SSTRIDE = 264;  // padded extended-state stride (S=257 max)

// ---------- fp16 raw-bit helpers (convert at consume, NOT at load) ----------
static __device__ __forceinline__ float lo_h(unsigned int u) {
  unsigned short s = (unsigned short)(u & 0xffffu);
  _Float16 h; __builtin_memcpy(&h, &s, 2); return (float)h;
}
static __device__ __forceinline__ float hi_h(unsigned int u) {
  unsigned short s = (unsigned short)(u >> 16);
  _Float16 h; __builtin_memcpy(&h, &s, 2); return (float)h;
}

// Gather kernel v2: stream each 4KB class-row coalesced into LDS, then gather
// em[(b*T+t)*SSTRIDE + s] = log2e * lp[b,t,ext[s]]  (NEGH where state invalid).
// One wave per (b,t) row; 4 waves/block; NO __syncthreads (waves exit early).
__global__ __launch_bounds__(256) void gather_kernel(
    const float* __restrict__ lp, const int* __restrict__ targets,
    const int* __restrict__ ilen, const int* __restrict__ tlen,
    _Float16* __restrict__ em, int B, int T, int C, int L) {
  __shared__ float rowbuf[4][1024];
  const int wave = threadIdx.x >> 6;
  const int lane = threadIdx.x & 63;
  const int row = blockIdx.x * 4 + wave;
  if (row >= B * T) return;
  const int b = row / T;
  const int t = row - b * T;
  if (t >= ilen[b]) return;                  // row never read by DP
  const int tl = tlen[b];
  const int* tg = targets + (size_t)b * L;

  // coalesced stream: 4 x float4 per lane = 4KB row -> LDS
  const float4* src = (const float4*)(lp + (size_t)row * C);
  float4* dstl = (float4*)rowbuf[wave];
#pragma unroll
  for (int k = 0; k < 4; ++k) dstl[lane + 64 * k] = src[lane + 64 * k];
  // same-wave DS ops are in-order; just drain lgkm before reading back
  asm volatile("s_waitcnt lgkmcnt(0)" ::: "memory");

  const float* rb = rowbuf[wave];
  _Float16* dst = em + (size_t)row * SSTRIDE;
  const float blank2 = rb[0] * LOG2E;
#pragma unroll
  for (int k = 0; k < 5; ++k) {
    int s = lane + 64 * k;                   // 0..319, write 0..263
    if (s >= SSTRIDE) break;
    float v;
    if (s & 1) {
      int li = (s - 1) >> 1;                 // <= 131
      v = (li < tl && li < L) ? rb[tg[li]] * LOG2E : NEGH;
    } else {
      v = ((s >> 1) <= tl) ? blank2 : NEGH;
    }
    dst[s] = (_Float16)v;
  }
}

// DP kernel: one wave per batch element, log2 domain.
// Lane l owns states 4l..4l+3 (a[0..3]) + redundant 4l+4 (a[4]).
// Prefetch ring holds RAW fp16 bits; converts happen only at consume.
__global__ __launch_bounds__(64) void ctc_dp_kernel(
    const _Float16* __restrict__ em, const int* __restrict__ targets,
    const int* __restrict__ ilen, const int* __restrict__ tlen,
    float* __restrict__ out, int T, int L) {
  const int b = blockIdx.x;
  const int l = threadIdx.x;
  const int len = ilen[b];
  const int tl = tlen[b];
  const int Sb = 2 * tl + 1;
  const int* tg = targets + (size_t)b * L;
  const _Float16* base = em + (size_t)b * T * SSTRIDE;

  // skip masks: only odd states (j=1,3 since s=4l+j parity == j parity)
  bool sk1, sk3;
  {
    int s1 = 4 * l + 1, s3 = 4 * l + 3;
    int li1 = (s1 - 1) >> 1, li3 = (s3 - 1) >> 1;
    sk1 = (s1 >= 3 && s1 < Sb) ? (tg[li1] != tg[li1 - 1]) : false;
    sk3 = (s3 < Sb) ? (tg[li3] != tg[li3 - 1]) : false;   // s3>=3 always
  }

  // t = 0: only states 0,1 alive (Sb >= 129 so both valid)
  float a[5];
#pragma unroll
  for (int j = 0; j < 5; ++j) {
    int s = 4 * l + j;
    a[j] = (s < 2) ? (float)base[s] : NEGV;
  }

  struct Raw { unsigned int x, y, z; };      // states 4l..4l+3 (x,y) + 4l+4 (z)
  auto loadraw = [&](Raw& r, int t) {
    const unsigned int* p = (const unsigned int*)(base + (size_t)t * SSTRIDE + 4 * l);
    uint2 v = *(const uint2*)p;              // 8B: states 4l..4l+3
    r.x = v.x; r.y = v.y;
    r.z = *(const unsigned short*)(p + 2);   // state 4l+4 (zero-extended)
  };

  auto step = [&](const Raw& r) {
    float g0 = lo_h(r.x), g1 = hi_h(r.x), g2 = lo_h(r.y), g3 = hi_h(r.y);
    float g4 = lo_h(r.z);
    float up1 = __shfl_up(a[3], 1, 64);      // alpha[4l-1]
    float up2 = __shfl_up(a[2], 1, 64);      // alpha[4l-2]
    if (l == 0) { up1 = NEGV; up2 = NEGV; }
    float n0, n1, n2, n3, n4;
    // even states: 2-way log2addexp
    {
      float m = fmaxf(a[0], up1);
      n0 = g0 + m + __builtin_amdgcn_logf(__builtin_amdgcn_exp2f(a[0] - m) +
                                          __builtin_amdgcn_exp2f(up1 - m));
    }
    {
      float m = fmaxf(a[2], a[1]);
      n2 = g2 + m + __builtin_amdgcn_logf(__builtin_amdgcn_exp2f(a[2] - m) +
                                          __builtin_amdgcn_exp2f(a[1] - m));
    }
    {
      float m = fmaxf(a[4], a[3]);
      n4 = g4 + m + __builtin_amdgcn_logf(__builtin_amdgcn_exp2f(a[4] - m) +
                                          __builtin_amdgcn_exp2f(a[3] - m));
    }
    // odd states: 3-way with skip
    {
      float q2 = sk1 ? up2 : NEGV;
      float m = fmaxf(a[1], fmaxf(a[0], q2));
      n1 = g1 + m + __builtin_amdgcn_logf(__builtin_amdgcn_exp2f(a[1] - m) +
                                          __builtin_amdgcn_exp2f(a[0] - m) +
                                          __builtin_amdgcn_exp2f(q2 - m));
    }
    {
      float q2 = sk3 ? a[1] : NEGV;
      float m = fmaxf(a[3], fmaxf(a[2], q2));
      n3 = g3 + m + __builtin_amdgcn_logf(__builtin_amdgcn_exp2f(a[3] - m) +
                                          __builtin_amdgcn_exp2f(a[2] - m) +
                                          __builtin_amdgcn_exp2f(q2 - m));
    }
    a[0] = n0; a[1] = n1; a[2] = n2; a[3] = n3; a[4] = n4;
  };

  constexpr int PD = 8;
  Raw ring[PD];
#pragma unroll
  for (int d = 0; d < PD; ++d) {
    int idx = 1 + d; if (idx >= len) idx = len - 1;
    loadraw(ring[d], idx);
  }
  int t = 1;
  for (; t + PD - 1 < len; t += PD) {
#pragma unroll
    for (int d = 0; d < PD; ++d) {
      step(ring[d]);
      int idx = t + d + PD; if (idx >= len) idx = len - 1;  // clamped rows never consumed
      loadraw(ring[d], idx);
    }
  }
  for (int d = 0; t < len; ++t, ++d) step(ring[d]);

  // epilogue: log2addexp(alpha[Sb-1], alpha[Sb-2]) * ln2; normalizer ~ 0 (log-softmax input)
  __shared__ float af[257];
#pragma unroll
  for (int j = 0; j < 4; ++j) af[4 * l + j] = a[j];
  if (l == 63) af[256] = a[4];
  __syncthreads();
  if (l == 0) {
    float a1 = af[Sb - 1];
    float a2 = af[Sb - 2];
    float m = fmaxf(a1, a2);
    float llh2 = m + __builtin_amdgcn_logf(__builtin_amdgcn_exp2f(a1 - m) +
                                           __builtin_amdgcn_exp2f(a2 - m));
    out[b] = -llh2 * LN2;
  }
}

extern "C" void kernel_launch(void* const* d_in, const int* in_sizes, int n_in,
                              void* d_out, int out_size, void* d_ws, size_t ws_size,
                              hipStream_t stream) {
  const float* lp = (const float*)d_in[0];
  const int* targets = (const int*)d_in[1];
  const int* ilen = (const int*)d_in[2];
  const int* tlen = (const int*)d_in[3];
  float* out = (float*)d_out;

  const int B = in_sizes[2];               // 32
  const int L = in_sizes[1] / B;           // 128
  const int C = 1024;                      // per reference
  const int T = in_sizes[0] / (B * C);     // 1600

  _Float16* em = (_Float16*)d_ws;          // B*T*SSTRIDE fp16 = ~27 MB

  const int rows = B * T;
  gather_kernel<<<(rows + 3) / 4, 256, 0, stream>>>(lp, targets, ilen, tlen, em, B, T, C, L);
  ctc_dp_kernel<<<B, 64, 0, stream>>>(em, targets, ilen, tlen, out, T, L);
}